// Round 1
// baseline (82.758 us; speedup 1.0000x reference)
//
#include <hip/hip_runtime.h>
#include <math.h>

#define NPRED 22743
#define NB 16
#define NT 20

// level boundaries: 76*76*3=17328, +38*38*3=4332 -> 21660, +19*19*3=1083 -> 22743
__device__ __constant__ float c_anch[9][2] = {
    {10.f,13.f},{16.f,30.f},{33.f,23.f},{30.f,61.f},{62.f,45.f},
    {59.f,119.f},{116.f,90.f},{156.f,198.f},{373.f,326.f}};

__device__ __forceinline__ float sigm(float x){ return 1.0f/(1.0f+expf(-x)); }

// map flat prediction index j in [0,22743) of image b to the source feature row
__device__ __forceinline__ const float* pred_ptr(const float* f0, const float* f1,
                                                 const float* f2, int b, int j,
                                                 int& fi, int& local){
    if (j < 17328){ fi = 0; local = j;          return f0 + ((size_t)b*17328 + local)*85; }
    if (j < 21660){ fi = 1; local = j - 17328;  return f1 + ((size_t)b*4332  + local)*85; }
    fi = 2; local = j - 21660;                  return f2 + ((size_t)b*1083  + local)*85; }

// ---------------- Kernel A: per-target losses + positive indices ----------------
__global__ void yolo_targets(const float* __restrict__ f0, const float* __restrict__ f1,
                             const float* __restrict__ f2,
                             const float* __restrict__ tb, const int* __restrict__ tlab,
                             const float* __restrict__ tsc,
                             int* __restrict__ pos_idx,
                             float* __restrict__ lbox_o, float* __restrict__ lobj_o,
                             float* __restrict__ lcls_o){
    const int b = blockIdx.x;
    const int t = threadIdx.x;
    __shared__ float sbox[32], sobj[32], scls[32];
    float mybox = 0.f, myobj = 0.f, mycls = 0.f;
    if (t < NT){
        const float* box = tb + ((size_t)b*NT + t)*4;
        const float cx = box[0], cy = box[1], tw = box[2], th = box[3];
        // wh-IoU argmax over 9 anchors (first max wins -> strict >)
        const float at = tw*th;
        int best = 0; float bestiou = -1.f;
        #pragma unroll
        for (int a = 0; a < 9; ++a){
            float aw = c_anch[a][0], ah = c_anch[a][1];
            float inter = fminf(tw,aw)*fminf(th,ah);
            float iou = inter/(at + aw*ah - inter);
            if (iou > bestiou){ bestiou = iou; best = a; }
        }
        const int fi = best/3, bidx = best%3;
        const float scale = (fi==0)?8.f:((fi==1)?16.f:32.f);
        const int   hh    = (fi==0)?76 :((fi==1)?38 :19);
        const int   start = (fi==0)?0  :((fi==1)?17328:21660);
        const float aw = c_anch[best][0], ah = c_anch[best][1];
        // cell + fractional offset, mirroring reference fp32 op order
        float sx = cx/scale, sy = cy/scale;
        float fx = sx - floorf(sx); if (fx == 0.f) fx = 1.f;
        float fy = sy - floorf(sy); if (fy == 0.f) fy = 1.f;
        const int tlx = (int)(sx - fx);
        const int tly = (int)(sy - fy);
        const float gtw = logf(tw/aw), gth = logf(th/ah);
        const int pidx = start + (tlx*hh + tly)*3 + bidx;
        pos_idx[b*NT + t] = pidx;
        int fdum, ldum;
        const float* p = pred_ptr(f0,f1,f2,b,pidx,fdum,ldum);
        // lbox partial: w * sum((pred_txywh - gt)^2) over 4 comps
        const float w = 2.f - gtw*gth;
        float d0 = sigm(p[0]) - fx;
        float d1 = sigm(p[1]) - fy;
        float d2 = p[2] - gtw;
        float d3 = p[3] - gth;
        mybox = w*(d0*d0 + d1*d1 + d2*d2 + d3*d3);
        // lobj partial: bce(sigmoid(p4), tscore)
        {
            float po = sigm(p[4]);
            float ts = tsc[b*NT + t];
            float lg  = fmaxf(logf(po),    -100.f);
            float lg1 = fmaxf(log1pf(-po), -100.f);
            myobj = -(ts*lg + (1.f-ts)*lg1);
        }
        // lcls partial: sum over 80 classes of bce vs one-hot
        {
            const int lab = tlab[b*NT + t];
            float s = 0.f;
            for (int c = 0; c < 80; ++c){
                float pc = sigm(p[5+c]);
                float lg  = fmaxf(logf(pc),    -100.f);
                float lg1 = fmaxf(log1pf(-pc), -100.f);
                float tt = (c == lab) ? 1.f : 0.f;
                s += -(tt*lg + (1.f-tt)*lg1);
            }
            mycls = s;
        }
    }
    sbox[t] = mybox; sobj[t] = myobj; scls[t] = mycls;
    __syncthreads();
    if (t == 0){
        float a = 0.f, o = 0.f, c = 0.f;
        for (int i = 0; i < NT; ++i){ a += sbox[i]; o += sobj[i]; c += scls[i]; }
        float lbox = a/(float)(NT*4);
        if (isinf(lbox)) lbox = 0.f;
        lbox_o[b] = lbox;
        lobj_o[b] = o/(float)NT;
        lcls_o[b] = c/(float)(NT*80);
    }
}

// ---------------- Kernel B: per-prediction noobj loss ----------------
__global__ void yolo_noobj(const float* __restrict__ f0, const float* __restrict__ f1,
                           const float* __restrict__ f2,
                           const float* __restrict__ tb, const int* __restrict__ pos_idx,
                           float* __restrict__ nsum, int* __restrict__ ncnt){
    const int b = blockIdx.y;
    const int j = blockIdx.x*blockDim.x + threadIdx.x;
    __shared__ float stb[NT][4];
    __shared__ int   spi[NT];
    if (threadIdx.x < NT*4) ((float*)stb)[threadIdx.x] = tb[(size_t)b*NT*4 + threadIdx.x];
    if (threadIdx.x >= 128 && threadIdx.x < 128+NT)
        spi[threadIdx.x-128] = pos_idx[b*NT + (threadIdx.x-128)];
    __syncthreads();

    float nb = 0.f; int cnt = 0;
    if (j < NPRED){
        int fi, local;
        const float* p = pred_ptr(f0,f1,f2,b,j,fi,local);
        const int   hh    = (fi==0)?76 :((fi==1)?38 :19);
        const float scale = (fi==0)?8.f:((fi==1)?16.f:32.f);
        const int cx = local/(hh*3);
        const int cy = (local/3)%hh;
        const int bidx = local%3;
        const float aw = c_anch[fi*3+bidx][0], ah = c_anch[fi*3+bidx][1];
        const float p0 = p[0], p1 = p[1], p2 = p[2], p3 = p[3], p4 = p[4];
        const float pcx = ((float)cx + sigm(p0))*scale;
        const float pcy = ((float)cy + sigm(p1))*scale;
        const float pw = aw*expf(p2);
        const float ph = ah*expf(p3);
        const float a1 = pw*ph;
        float maxiou = -INFINITY;
        #pragma unroll
        for (int t = 0; t < NT; ++t){
            float tcx = stb[t][0], tcy = stb[t][1], tw = stb[t][2], th = stb[t][3];
            float ltx = fmaxf(pcx - pw*0.5f, tcx - tw*0.5f);
            float lty = fmaxf(pcy - ph*0.5f, tcy - th*0.5f);
            float rbx = fminf(pcx + pw*0.5f, tcx + tw*0.5f);
            float rby = fminf(pcy + ph*0.5f, tcy + th*0.5f);
            float iw = fmaxf(rbx - ltx, 0.f);
            float ih = fmaxf(rby - lty, 0.f);
            float inter = iw*ih;
            float iou = inter/(a1 + tw*th - inter);
            maxiou = fmaxf(maxiou, iou);
        }
        bool pos = false;
        #pragma unroll
        for (int t = 0; t < NT; ++t) pos = pos || (spi[t] == j);
        if (maxiou < 0.5f && !pos){
            float po = sigm(p4);
            nb = -fmaxf(log1pf(-po), -100.f);
            cnt = 1;
        }
    }
    // block reduction
    __shared__ float rs[256];
    __shared__ int   rc[256];
    rs[threadIdx.x] = nb; rc[threadIdx.x] = cnt;
    __syncthreads();
    for (int s = 128; s > 0; s >>= 1){
        if (threadIdx.x < s){ rs[threadIdx.x] += rs[threadIdx.x+s]; rc[threadIdx.x] += rc[threadIdx.x+s]; }
        __syncthreads();
    }
    if (threadIdx.x == 0){
        atomicAdd(&nsum[b], rs[0]);
        atomicAdd(&ncnt[b], rc[0]);
    }
}

// ---------------- Kernel C: finalize 4 outputs ----------------
__global__ void yolo_final(const float* __restrict__ lbox, const float* __restrict__ lobj,
                           const float* __restrict__ lcls, const float* __restrict__ nsum,
                           const int* __restrict__ ncnt, float* __restrict__ out){
    if (threadIdx.x == 0 && blockIdx.x == 0){
        float sb = 0.f, so = 0.f, sc = 0.f, sn = 0.f;
        for (int b = 0; b < NB; ++b){
            sb += lbox[b]; so += lobj[b]; sc += lcls[b];
            int c = ncnt[b];
            float denom = (float)(c > 1 ? c : 1);
            sn += nsum[b]/denom;
        }
        out[0] = sb/(float)NB;          // L_COORD * lbox.mean()
        out[1] = sc/(float)NB;          // L_CLS   * lcls.mean()
        out[2] = so/(float)NB;          // L_OBJ   * lobj.mean()
        out[3] = 0.5f*sn/(float)NB;     // L_NOOBJ * lnoobj.mean()
    }
}

extern "C" void kernel_launch(void* const* d_in, const int* in_sizes, int n_in,
                              void* d_out, int out_size, void* d_ws, size_t ws_size,
                              hipStream_t stream) {
    const float* f0  = (const float*)d_in[0];
    const float* f1  = (const float*)d_in[1];
    const float* f2  = (const float*)d_in[2];
    const float* tb  = (const float*)d_in[3];
    const int*   tlab= (const int*)  d_in[4];
    const float* tsc = (const float*)d_in[5];
    float* out = (float*)d_out;

    // ws layout (all within first 1600 B)
    char* ws = (char*)d_ws;
    int*   pos_idx = (int*)ws;              // 16*20 ints = 1280 B
    float* lbox    = (float*)(ws + 1280);   // 16 f
    float* lobj    = (float*)(ws + 1344);   // 16 f
    float* lcls    = (float*)(ws + 1408);   // 16 f
    float* nsum    = (float*)(ws + 1472);   // 16 f
    int*   ncnt    = (int*)  (ws + 1536);   // 16 i

    hipMemsetAsync(d_ws, 0, 1600, stream);

    yolo_targets<<<NB, 32, 0, stream>>>(f0, f1, f2, tb, tlab, tsc,
                                        pos_idx, lbox, lobj, lcls);

    dim3 gridB((NPRED + 255)/256, NB);
    yolo_noobj<<<gridB, 256, 0, stream>>>(f0, f1, f2, tb, pos_idx, nsum, ncnt);

    yolo_final<<<1, 64, 0, stream>>>(lbox, lobj, lcls, nsum, ncnt, out);
}

// Round 2
// 36.860 us; speedup vs baseline: 2.2452x; 2.2452x over previous
//
#include <hip/hip_runtime.h>
#include <math.h>

#define NPRED 22743
#define NB 16
#define NT 20

// level boundaries: 76*76*3=17328, +38*38*3=4332 -> 21660, +19*19*3=1083 -> 22743
__device__ __constant__ float c_anch[9][2] = {
    {10.f,13.f},{16.f,30.f},{33.f,23.f},{30.f,61.f},{62.f,45.f},
    {59.f,119.f},{116.f,90.f},{156.f,198.f},{373.f,326.f}};

__device__ __forceinline__ float sigm(float x){ return 1.0f/(1.0f+expf(-x)); }

// map flat prediction index j in [0,22743) of image b to the source feature row
__device__ __forceinline__ const float* pred_ptr(const float* f0, const float* f1,
                                                 const float* f2, int b, int j,
                                                 int& fi, int& local){
    if (j < 17328){ fi = 0; local = j;          return f0 + ((size_t)b*17328 + local)*85; }
    if (j < 21660){ fi = 1; local = j - 17328;  return f1 + ((size_t)b*4332  + local)*85; }
    fi = 2; local = j - 21660;                  return f2 + ((size_t)b*1083  + local)*85; }

// ---------------- Kernel A: one wave per target ----------------
__global__ __launch_bounds__(64) void yolo_targets(
        const float* __restrict__ f0, const float* __restrict__ f1,
        const float* __restrict__ f2,
        const float* __restrict__ tb, const int* __restrict__ tlab,
        const float* __restrict__ tsc,
        int* __restrict__ pos_idx,
        float* __restrict__ pbox, float* __restrict__ pobj,
        float* __restrict__ pcls,
        float* __restrict__ nsum, int* __restrict__ ncnt){
    const int bt = blockIdx.x;            // 0..319
    const int b  = bt / NT;
    const int t  = bt % NT;
    const int lane = threadIdx.x;         // 0..63

    // zero kernel-B accumulators (runs before kernel B on same stream)
    if (t == 0 && lane == 0){ nsum[b] = 0.f; ncnt[b] = 0; }

    const float* box = tb + ((size_t)b*NT + t)*4;
    const float cx = box[0], cy = box[1], tw = box[2], th = box[3];

    // wh-IoU argmax over 9 anchors (wave-uniform; first max wins -> strict >)
    const float at = tw*th;
    int best = 0; float bestiou = -1.f;
    #pragma unroll
    for (int a = 0; a < 9; ++a){
        float aw = c_anch[a][0], ah = c_anch[a][1];
        float inter = fminf(tw,aw)*fminf(th,ah);
        float iou = inter/(at + aw*ah - inter);
        if (iou > bestiou){ bestiou = iou; best = a; }
    }
    const int fi = best/3, bidx = best%3;
    const float scale = (fi==0)?8.f:((fi==1)?16.f:32.f);
    const int   hh    = (fi==0)?76 :((fi==1)?38 :19);
    const int   start = (fi==0)?0  :((fi==1)?17328:21660);
    const float aw = c_anch[best][0], ah = c_anch[best][1];

    float sx = cx/scale, sy = cy/scale;
    float fx = sx - floorf(sx); if (fx == 0.f) fx = 1.f;
    float fy = sy - floorf(sy); if (fy == 0.f) fy = 1.f;
    const int tlx = (int)(sx - fx);
    const int tly = (int)(sy - fy);
    const float gtw = logf(tw/aw), gth = logf(th/ah);
    const int pidx = start + (tlx*hh + tly)*3 + bidx;

    int fdum, ldum;
    const float* p = pred_ptr(f0,f1,f2,b,pidx,fdum,ldum);

    // class BCE spread across lanes (c = lane, lane+64)
    const int lab = tlab[b*NT + t];
    float s = 0.f;
    #pragma unroll
    for (int c = lane; c < 80; c += 64){
        float pc = sigm(p[5+c]);
        float lg  = fmaxf(logf(pc),    -100.f);
        float lg1 = fmaxf(log1pf(-pc), -100.f);
        float tt = (c == lab) ? 1.f : 0.f;
        s += -(tt*lg + (1.f-tt)*lg1);
    }
    #pragma unroll
    for (int off = 32; off > 0; off >>= 1) s += __shfl_down(s, off);

    if (lane == 0){
        pos_idx[b*NT + t] = pidx;
        const float w = 2.f - gtw*gth;
        float d0 = sigm(p[0]) - fx;
        float d1 = sigm(p[1]) - fy;
        float d2 = p[2] - gtw;
        float d3 = p[3] - gth;
        pbox[bt] = w*(d0*d0 + d1*d1 + d2*d2 + d3*d3);
        float po = sigm(p[4]);
        float ts = tsc[b*NT + t];
        float lg  = fmaxf(logf(po),    -100.f);
        float lg1 = fmaxf(log1pf(-po), -100.f);
        pobj[bt] = -(ts*lg + (1.f-ts)*lg1);
        pcls[bt] = s;
    }
}

// ---------------- Kernel B: per-prediction noobj loss ----------------
__global__ __launch_bounds__(256) void yolo_noobj(
        const float* __restrict__ f0, const float* __restrict__ f1,
        const float* __restrict__ f2,
        const float* __restrict__ tb, const int* __restrict__ pos_idx,
        float* __restrict__ nsum, int* __restrict__ ncnt){
    const int b = blockIdx.y;
    const int j = blockIdx.x*blockDim.x + threadIdx.x;
    __shared__ float stb[NT][4];
    __shared__ int   spi[NT];
    if (threadIdx.x < NT*4) ((float*)stb)[threadIdx.x] = tb[(size_t)b*NT*4 + threadIdx.x];
    if (threadIdx.x >= 128 && threadIdx.x < 128+NT)
        spi[threadIdx.x-128] = pos_idx[b*NT + (threadIdx.x-128)];
    __syncthreads();

    float nb = 0.f; int cnt = 0;
    if (j < NPRED){
        int fi, local;
        const float* p = pred_ptr(f0,f1,f2,b,j,fi,local);
        const int   hh    = (fi==0)?76 :((fi==1)?38 :19);
        const float scale = (fi==0)?8.f:((fi==1)?16.f:32.f);
        const int cx = local/(hh*3);
        const int cy = (local/3)%hh;
        const int bidx = local%3;
        const float aw = c_anch[fi*3+bidx][0], ah = c_anch[fi*3+bidx][1];
        const float p0 = p[0], p1 = p[1], p2 = p[2], p3 = p[3], p4 = p[4];
        const float pcx = ((float)cx + sigm(p0))*scale;
        const float pcy = ((float)cy + sigm(p1))*scale;
        const float pw = aw*expf(p2);
        const float ph = ah*expf(p3);
        const float a1 = pw*ph;
        float maxiou = -INFINITY;
        #pragma unroll
        for (int t = 0; t < NT; ++t){
            float tcx = stb[t][0], tcy = stb[t][1], tw = stb[t][2], th = stb[t][3];
            float ltx = fmaxf(pcx - pw*0.5f, tcx - tw*0.5f);
            float lty = fmaxf(pcy - ph*0.5f, tcy - th*0.5f);
            float rbx = fminf(pcx + pw*0.5f, tcx + tw*0.5f);
            float rby = fminf(pcy + ph*0.5f, tcy + th*0.5f);
            float iw = fmaxf(rbx - ltx, 0.f);
            float ih = fmaxf(rby - lty, 0.f);
            float inter = iw*ih;
            float iou = inter/(a1 + tw*th - inter);
            maxiou = fmaxf(maxiou, iou);
        }
        bool pos = false;
        #pragma unroll
        for (int t = 0; t < NT; ++t) pos = pos || (spi[t] == j);
        if (maxiou < 0.5f && !pos){
            float po = sigm(p4);
            nb = -fmaxf(log1pf(-po), -100.f);
            cnt = 1;
        }
    }
    // wave shuffle reduce, then cross-wave via LDS
    #pragma unroll
    for (int off = 32; off > 0; off >>= 1){
        nb  += __shfl_down(nb, off);
        cnt += __shfl_down(cnt, off);
    }
    __shared__ float ws_s[4];
    __shared__ int   ws_c[4];
    const int wid = threadIdx.x >> 6;
    if ((threadIdx.x & 63) == 0){ ws_s[wid] = nb; ws_c[wid] = cnt; }
    __syncthreads();
    if (threadIdx.x == 0){
        float tsum = ws_s[0]+ws_s[1]+ws_s[2]+ws_s[3];
        int   tcnt = ws_c[0]+ws_c[1]+ws_c[2]+ws_c[3];
        atomicAdd(&nsum[b], tsum);
        atomicAdd(&ncnt[b], tcnt);
    }
}

// ---------------- Kernel C: finalize 4 outputs ----------------
__global__ __launch_bounds__(64) void yolo_final(
        const float* __restrict__ pbox, const float* __restrict__ pobj,
        const float* __restrict__ pcls, const float* __restrict__ nsum,
        const int* __restrict__ ncnt, float* __restrict__ out){
    const int lane = threadIdx.x;
    float sb = 0.f, so = 0.f, sc = 0.f, sn = 0.f;
    if (lane < NB){
        float a = 0.f, o = 0.f, c = 0.f;
        for (int t = 0; t < NT; ++t){
            a += pbox[lane*NT + t];
            o += pobj[lane*NT + t];
            c += pcls[lane*NT + t];
        }
        float lb = a/(float)(NT*4);
        if (isinf(lb)) lb = 0.f;
        sb = lb;
        so = o/(float)NT;
        sc = c/(float)(NT*80);
        int cc = ncnt[lane];
        sn = nsum[lane]/(float)(cc > 1 ? cc : 1);
    }
    #pragma unroll
    for (int off = 8; off > 0; off >>= 1){
        sb += __shfl_down(sb, off);
        so += __shfl_down(so, off);
        sc += __shfl_down(sc, off);
        sn += __shfl_down(sn, off);
    }
    if (lane == 0){
        out[0] = sb/(float)NB;          // L_COORD * lbox.mean()
        out[1] = sc/(float)NB;          // L_CLS   * lcls.mean()
        out[2] = so/(float)NB;          // L_OBJ   * lobj.mean()
        out[3] = 0.5f*sn/(float)NB;     // L_NOOBJ * lnoobj.mean()
    }
}

extern "C" void kernel_launch(void* const* d_in, const int* in_sizes, int n_in,
                              void* d_out, int out_size, void* d_ws, size_t ws_size,
                              hipStream_t stream) {
    const float* f0  = (const float*)d_in[0];
    const float* f1  = (const float*)d_in[1];
    const float* f2  = (const float*)d_in[2];
    const float* tb  = (const float*)d_in[3];
    const int*   tlab= (const int*)  d_in[4];
    const float* tsc = (const float*)d_in[5];
    float* out = (float*)d_out;

    // ws layout
    char* ws = (char*)d_ws;
    int*   pos_idx = (int*)ws;              // 320 ints  = 1280 B
    float* pbox    = (float*)(ws + 1280);   // 320 f     = 1280 B
    float* pobj    = (float*)(ws + 2560);   // 320 f
    float* pcls    = (float*)(ws + 3840);   // 320 f
    float* nsum    = (float*)(ws + 5120);   // 16 f
    int*   ncnt    = (int*)  (ws + 5184);   // 16 i

    yolo_targets<<<NB*NT, 64, 0, stream>>>(f0, f1, f2, tb, tlab, tsc,
                                           pos_idx, pbox, pobj, pcls, nsum, ncnt);

    dim3 gridB((NPRED + 255)/256, NB);
    yolo_noobj<<<gridB, 256, 0, stream>>>(f0, f1, f2, tb, pos_idx, nsum, ncnt);

    yolo_final<<<1, 64, 0, stream>>>(pbox, pobj, pcls, nsum, ncnt, out);
}

// Round 3
// 33.099 us; speedup vs baseline: 2.5004x; 1.1136x over previous
//
#include <hip/hip_runtime.h>
#include <math.h>

#define NPRED 22743
#define NB 16
#define NT 20
#define NBLK 89            // noobj blocks per image: 89*256 = 22784 >= 22743

__device__ __constant__ float c_anch[9][2] = {
    {10.f,13.f},{16.f,30.f},{33.f,23.f},{30.f,61.f},{62.f,45.f},
    {59.f,119.f},{116.f,90.f},{156.f,198.f},{373.f,326.f}};

__device__ __forceinline__ float sigm(float x){ return 1.0f/(1.0f+expf(-x)); }

__device__ __forceinline__ const float* pred_ptr(const float* f0, const float* f1,
                                                 const float* f2, int b, int j,
                                                 int& fi, int& local){
    if (j < 17328){ fi = 0; local = j;          return f0 + ((size_t)b*17328 + local)*85; }
    if (j < 21660){ fi = 1; local = j - 17328;  return f1 + ((size_t)b*4332  + local)*85; }
    fi = 2; local = j - 21660;                  return f2 + ((size_t)b*1083  + local)*85; }

// positive index for one target box (depends only on the box, not features)
__device__ __forceinline__ void target_decode(float cx, float cy, float tw, float th,
                                              int& pidx, float& fx, float& fy,
                                              float& gtw, float& gth){
    const float at = tw*th;
    int best = 0; float bestiou = -1.f;
    #pragma unroll
    for (int a = 0; a < 9; ++a){
        float aw = c_anch[a][0], ah = c_anch[a][1];
        float inter = fminf(tw,aw)*fminf(th,ah);
        float iou = inter/(at + aw*ah - inter);
        if (iou > bestiou){ bestiou = iou; best = a; }
    }
    const int fi = best/3, bidx = best%3;
    const float scale = (fi==0)?8.f:((fi==1)?16.f:32.f);
    const int   hh    = (fi==0)?76 :((fi==1)?38 :19);
    const int   start = (fi==0)?0  :((fi==1)?17328:21660);
    const float aw = c_anch[best][0], ah = c_anch[best][1];
    float sx = cx/scale, sy = cy/scale;
    fx = sx - floorf(sx); if (fx == 0.f) fx = 1.f;
    fy = sy - floorf(sy); if (fy == 0.f) fy = 1.f;
    const int tlx = (int)(sx - fx);
    const int tly = (int)(sy - fy);
    gtw = logf(tw/aw); gth = logf(th/ah);
    pidx = start + (tlx*hh + tly)*3 + bidx;
}

// ---------------- Fused kernel: noobj partials + per-target losses ----------------
__global__ __launch_bounds__(256) void yolo_fused(
        const float* __restrict__ f0, const float* __restrict__ f1,
        const float* __restrict__ f2,
        const float* __restrict__ tb, const int* __restrict__ tlab,
        const float* __restrict__ tsc,
        float* __restrict__ part_s, int* __restrict__ part_c,
        float* __restrict__ pboxI, float* __restrict__ pobjI,
        float* __restrict__ pclsI){
    const int b   = blockIdx.y;
    const int x   = blockIdx.x;
    const int tid = threadIdx.x;

    if (x < NBLK){
        // ---- noobj path ----
        __shared__ float stb[NT][4];
        __shared__ int   spi[NT];
        if (tid < NT*4) ((float*)stb)[tid] = tb[(size_t)b*NT*4 + tid];
        // wave 1 recomputes positive indices straight from global tb
        if (tid >= 96 && tid < 96+NT){
            const int t = tid - 96;
            const float* box = tb + ((size_t)b*NT + t)*4;
            int pidx; float fx, fy, gw, gh;
            target_decode(box[0], box[1], box[2], box[3], pidx, fx, fy, gw, gh);
            spi[t] = pidx;
        }
        __syncthreads();

        const int j = x*256 + tid;
        float nb = 0.f; int cnt = 0;
        if (j < NPRED){
            int fi, local;
            const float* p = pred_ptr(f0,f1,f2,b,j,fi,local);
            const int   hh    = (fi==0)?76 :((fi==1)?38 :19);
            const float scale = (fi==0)?8.f:((fi==1)?16.f:32.f);
            const int cx = local/(hh*3);
            const int cy = (local/3)%hh;
            const int bidx = local%3;
            const float aw = c_anch[fi*3+bidx][0], ah = c_anch[fi*3+bidx][1];
            const float p0 = p[0], p1 = p[1], p2 = p[2], p3 = p[3], p4 = p[4];
            const float pcx = ((float)cx + sigm(p0))*scale;
            const float pcy = ((float)cy + sigm(p1))*scale;
            const float pw = aw*expf(p2);
            const float ph = ah*expf(p3);
            const float a1 = pw*ph;
            float maxiou = -INFINITY;
            #pragma unroll
            for (int t = 0; t < NT; ++t){
                float tcx = stb[t][0], tcy = stb[t][1], tw = stb[t][2], th = stb[t][3];
                float ltx = fmaxf(pcx - pw*0.5f, tcx - tw*0.5f);
                float lty = fmaxf(pcy - ph*0.5f, tcy - th*0.5f);
                float rbx = fminf(pcx + pw*0.5f, tcx + tw*0.5f);
                float rby = fminf(pcy + ph*0.5f, tcy + th*0.5f);
                float iw = fmaxf(rbx - ltx, 0.f);
                float ih = fmaxf(rby - lty, 0.f);
                float inter = iw*ih;
                float iou = inter/(a1 + tw*th - inter);
                maxiou = fmaxf(maxiou, iou);
            }
            bool pos = false;
            #pragma unroll
            for (int t = 0; t < NT; ++t) pos = pos || (spi[t] == j);
            if (maxiou < 0.5f && !pos){
                float po = sigm(p4);
                nb = -fmaxf(log1pf(-po), -100.f);
                cnt = 1;
            }
        }
        #pragma unroll
        for (int off = 32; off > 0; off >>= 1){
            nb  += __shfl_down(nb, off);
            cnt += __shfl_down(cnt, off);
        }
        __shared__ float ws_s[4];
        __shared__ int   ws_c[4];
        const int wid = tid >> 6;
        if ((tid & 63) == 0){ ws_s[wid] = nb; ws_c[wid] = cnt; }
        __syncthreads();
        if (tid == 0){
            part_s[b*NBLK + x] = ws_s[0]+ws_s[1]+ws_s[2]+ws_s[3];
            part_c[b*NBLK + x] = ws_c[0]+ws_c[1]+ws_c[2]+ws_c[3];
        }
    } else {
        // ---- per-target path (one block per image) ----
        const int w    = tid >> 6;    // wave 0..3
        const int lane = tid & 63;
        float abox = 0.f, aobj = 0.f, acls = 0.f;
        for (int t = w; t < NT; t += 4){
            const float* box = tb + ((size_t)b*NT + t)*4;
            const float cx = box[0], cy = box[1], tw = box[2], th = box[3];
            int pidx; float fx, fy, gtw, gth;
            target_decode(cx, cy, tw, th, pidx, fx, fy, gtw, gth);
            int fdum, ldum;
            const float* p = pred_ptr(f0,f1,f2,b,pidx,fdum,ldum);
            // class BCE over lanes: c = lane, then c = 64+lane (16 lanes)
            const int lab = tlab[b*NT + t];
            float s = 0.f;
            {
                float pc = sigm(p[5+lane]);
                float lg  = fmaxf(logf(pc),    -100.f);
                float lg1 = fmaxf(log1pf(-pc), -100.f);
                float tt = (lane == lab) ? 1.f : 0.f;
                s = -(tt*lg + (1.f-tt)*lg1);
            }
            if (lane < 16){
                int c = 64 + lane;
                float pc = sigm(p[5+c]);
                float lg  = fmaxf(logf(pc),    -100.f);
                float lg1 = fmaxf(log1pf(-pc), -100.f);
                float tt = (c == lab) ? 1.f : 0.f;
                s += -(tt*lg + (1.f-tt)*lg1);
            }
            #pragma unroll
            for (int off = 32; off > 0; off >>= 1) s += __shfl_down(s, off);
            if (lane == 0){
                const float w2 = 2.f - gtw*gth;
                float d0 = sigm(p[0]) - fx;
                float d1 = sigm(p[1]) - fy;
                float d2 = p[2] - gtw;
                float d3 = p[3] - gth;
                abox += w2*(d0*d0 + d1*d1 + d2*d2 + d3*d3);
                float po = sigm(p[4]);
                float ts = tsc[b*NT + t];
                float lg  = fmaxf(logf(po),    -100.f);
                float lg1 = fmaxf(log1pf(-po), -100.f);
                aobj += -(ts*lg + (1.f-ts)*lg1);
                acls += s;
            }
        }
        __shared__ float sA[4], sO[4], sC[4];
        if (lane == 0){ sA[w] = abox; sO[w] = aobj; sC[w] = acls; }
        __syncthreads();
        if (tid == 0){
            pboxI[b] = sA[0]+sA[1]+sA[2]+sA[3];
            pobjI[b] = sO[0]+sO[1]+sO[2]+sO[3];
            pclsI[b] = sC[0]+sC[1]+sC[2]+sC[3];
        }
    }
}

// ---------------- Kernel C: final reduction ----------------
__global__ __launch_bounds__(256) void yolo_final(
        const float* __restrict__ part_s, const int* __restrict__ part_c,
        const float* __restrict__ pboxI, const float* __restrict__ pobjI,
        const float* __restrict__ pclsI, float* __restrict__ out){
    const int tid  = threadIdx.x;
    const int w    = tid >> 6;
    const int lane = tid & 63;
    __shared__ float rb[NB], ro[NB], rc[NB], rn[NB];
    for (int b = w; b < NB; b += 4){
        float s = 0.f; int c = 0;
        if (lane < NBLK){ s = part_s[b*NBLK + lane]; c = part_c[b*NBLK + lane]; }
        if (lane + 64 < NBLK){ s += part_s[b*NBLK + lane + 64]; c += part_c[b*NBLK + lane + 64]; }
        #pragma unroll
        for (int off = 32; off > 0; off >>= 1){
            s += __shfl_down(s, off);
            c += __shfl_down(c, off);
        }
        if (lane == 0){
            float lb = pboxI[b]/(float)(NT*4);
            if (isinf(lb)) lb = 0.f;
            rb[b] = lb;
            ro[b] = pobjI[b]/(float)NT;
            rc[b] = pclsI[b]/(float)(NT*80);
            rn[b] = s/(float)(c > 1 ? c : 1);
        }
    }
    __syncthreads();
    if (tid == 0){
        float sb=0.f, so=0.f, sc=0.f, sn=0.f;
        for (int b = 0; b < NB; ++b){ sb += rb[b]; so += ro[b]; sc += rc[b]; sn += rn[b]; }
        out[0] = sb/(float)NB;          // L_COORD * lbox.mean()
        out[1] = sc/(float)NB;          // L_CLS   * lcls.mean()
        out[2] = so/(float)NB;          // L_OBJ   * lobj.mean()
        out[3] = 0.5f*sn/(float)NB;     // L_NOOBJ * lnoobj.mean()
    }
}

extern "C" void kernel_launch(void* const* d_in, const int* in_sizes, int n_in,
                              void* d_out, int out_size, void* d_ws, size_t ws_size,
                              hipStream_t stream) {
    const float* f0  = (const float*)d_in[0];
    const float* f1  = (const float*)d_in[1];
    const float* f2  = (const float*)d_in[2];
    const float* tb  = (const float*)d_in[3];
    const int*   tlab= (const int*)  d_in[4];
    const float* tsc = (const float*)d_in[5];
    float* out = (float*)d_out;

    // ws layout — every slot written every call; no init needed
    char* ws = (char*)d_ws;
    float* part_s = (float*)ws;                       // 16*89 floats = 5696 B
    int*   part_c = (int*)  (ws + 5696);              // 16*89 ints  = 5696 B
    float* pboxI  = (float*)(ws + 11392);             // 16 f
    float* pobjI  = (float*)(ws + 11456);             // 16 f
    float* pclsI  = (float*)(ws + 11520);             // 16 f

    dim3 grid(NBLK + 1, NB);
    yolo_fused<<<grid, 256, 0, stream>>>(f0, f1, f2, tb, tlab, tsc,
                                         part_s, part_c, pboxI, pobjI, pclsI);
    yolo_final<<<1, 256, 0, stream>>>(part_s, part_c, pboxI, pobjI, pclsI, out);
}

// Round 4
// 27.632 us; speedup vs baseline: 2.9951x; 1.1979x over previous
//
#include <hip/hip_runtime.h>
#include <math.h>

#define NPRED 22743
#define NB 16
#define NT 20
#define NBLK2 45           // ceil(22743 / 512) noobj blocks per image (2 rows/thread)
#define NTBLK 5            // target blocks per image (4 waves x 1 target)

__device__ __constant__ float c_anch[9][2] = {
    {10.f,13.f},{16.f,30.f},{33.f,23.f},{30.f,61.f},{62.f,45.f},
    {59.f,119.f},{116.f,90.f},{156.f,198.f},{373.f,326.f}};

__device__ __forceinline__ float sigm(float x){ return 1.0f/(1.0f+expf(-x)); }

__device__ __forceinline__ const float* row_base(const float* f0, const float* f1,
                                                 const float* f2, int b, int j){
    if (j < 17328) return f0 + ((size_t)b*17328 + j)*85;
    if (j < 21660) return f1 + ((size_t)b*4332  + (j-17328))*85;
    return f2 + ((size_t)b*1083 + (j-21660))*85;
}

// constant-divisor geometry per level
__device__ __forceinline__ void row_geom(int j, float& scale, int& cx, int& cy, int& aidx){
    int local, fi;
    if (j < 17328){      local = j;        scale = 8.f;  cx = local/228; cy = (local/3)%76; fi = 0; }
    else if (j < 21660){ local = j-17328;  scale = 16.f; cx = local/114; cy = (local/3)%38; fi = 1; }
    else {               local = j-21660;  scale = 32.f; cx = local/57;  cy = (local/3)%19; fi = 2; }
    aidx = fi*3 + local%3;
}

__device__ __forceinline__ int best_anchor(float tw, float th){
    const float at = tw*th;
    int best = 0; float bi = -1.f;
    #pragma unroll
    for (int a = 0; a < 9; ++a){
        float aw = c_anch[a][0], ah = c_anch[a][1];
        float inter = fminf(tw,aw)*fminf(th,ah);
        float iou = inter/(at + aw*ah - inter);
        if (iou > bi){ bi = iou; best = a; }
    }
    return best;
}

// positive index only (no logf) — for the noobj-block spi recompute
__device__ __forceinline__ int pos_index(float cx, float cy, float tw, float th){
    const int best = best_anchor(tw,th);
    const int fi = best/3, bidx = best%3;
    const float scale = (fi==0)?8.f:((fi==1)?16.f:32.f);
    const int   hh    = (fi==0)?76 :((fi==1)?38 :19);
    const int   start = (fi==0)?0  :((fi==1)?17328:21660);
    float sx = cx/scale, sy = cy/scale;
    float fx = sx - floorf(sx); if (fx == 0.f) fx = 1.f;
    float fy = sy - floorf(sy); if (fy == 0.f) fy = 1.f;
    const int tlx = (int)(sx - fx);
    const int tly = (int)(sy - fy);
    return start + (tlx*hh + tly)*3 + bidx;
}

// full decode (with logf) — for the target-loss path
__device__ __forceinline__ void target_decode(float cx, float cy, float tw, float th,
                                              int& pidx, float& fx, float& fy,
                                              float& gtw, float& gth){
    const int best = best_anchor(tw,th);
    const int fi = best/3, bidx = best%3;
    const float scale = (fi==0)?8.f:((fi==1)?16.f:32.f);
    const int   hh    = (fi==0)?76 :((fi==1)?38 :19);
    const int   start = (fi==0)?0  :((fi==1)?17328:21660);
    const float aw = c_anch[best][0], ah = c_anch[best][1];
    float sx = cx/scale, sy = cy/scale;
    fx = sx - floorf(sx); if (fx == 0.f) fx = 1.f;
    fy = sy - floorf(sy); if (fy == 0.f) fy = 1.f;
    const int tlx = (int)(sx - fx);
    const int tly = (int)(sy - fy);
    gtw = logf(tw/aw); gth = logf(th/ah);
    pidx = start + (tlx*hh + tly)*3 + bidx;
}

// one prediction row's noobj contribution
__device__ __forceinline__ void noobj_row(int j, const float r[5],
                                          const float4* stb4, const int* spi,
                                          float& nb, int& cnt){
    float scale; int cx, cy, aidx;
    row_geom(j, scale, cx, cy, aidx);
    const float aw = c_anch[aidx][0], ah = c_anch[aidx][1];
    const float pcx = ((float)cx + sigm(r[0]))*scale;
    const float pcy = ((float)cy + sigm(r[1]))*scale;
    const float pw = aw*expf(r[2]);
    const float ph = ah*expf(r[3]);
    const float a1 = pw*ph;
    float maxiou = -INFINITY;
    #pragma unroll
    for (int t = 0; t < NT; ++t){
        float4 T = stb4[t];
        float ltx = fmaxf(pcx - pw*0.5f, T.x - T.z*0.5f);
        float lty = fmaxf(pcy - ph*0.5f, T.y - T.w*0.5f);
        float rbx = fminf(pcx + pw*0.5f, T.x + T.z*0.5f);
        float rby = fminf(pcy + ph*0.5f, T.y + T.w*0.5f);
        float iw = fmaxf(rbx - ltx, 0.f);
        float ih = fmaxf(rby - lty, 0.f);
        float inter = iw*ih;
        float iou = inter/(a1 + T.z*T.w - inter);
        maxiou = fmaxf(maxiou, iou);
    }
    bool pos = false;
    #pragma unroll
    for (int t = 0; t < NT; ++t) pos = pos || (spi[t] == j);
    if (maxiou < 0.5f && !pos){
        // -max(log1p(-sigmoid(x)),-100) == min(softplus(x),100)
        nb += fminf(log1pf(expf(r[4])), 100.f);
        cnt += 1;
    }
}

// ---------------- Fused kernel ----------------
__global__ __launch_bounds__(256) void yolo_fused(
        const float* __restrict__ f0, const float* __restrict__ f1,
        const float* __restrict__ f2,
        const float* __restrict__ tb, const int* __restrict__ tlab,
        const float* __restrict__ tsc,
        float* __restrict__ part_s, int* __restrict__ part_c,
        float* __restrict__ pbox, float* __restrict__ pobj,
        float* __restrict__ pcls){
    const int b   = blockIdx.y;
    const int x   = blockIdx.x;
    const int tid = threadIdx.x;

    if (x < NBLK2){
        // ---- noobj path: 2 rows per thread ----
        __shared__ float4 stb4[NT];
        __shared__ int    spi[NT];
        if (tid < NT) stb4[tid] = ((const float4*)tb)[b*NT + tid];
        if (tid >= 96 && tid < 96+NT){
            float4 box = ((const float4*)tb)[b*NT + (tid-96)];
            spi[tid-96] = pos_index(box.x, box.y, box.z, box.w);
        }
        __syncthreads();

        const int j0 = x*512 + tid;
        const int j1 = j0 + 256;
        const bool a0 = (j0 < NPRED), a1 = (j1 < NPRED);
        const float* P0 = row_base(f0,f1,f2,b, a0 ? j0 : 0);
        const float* P1 = row_base(f0,f1,f2,b, a1 ? j1 : 0);
        float r0[5], r1[5];
        #pragma unroll
        for (int k = 0; k < 5; ++k) r0[k] = P0[k];
        #pragma unroll
        for (int k = 0; k < 5; ++k) r1[k] = P1[k];

        float nb = 0.f; int cnt = 0;
        if (a0) noobj_row(j0, r0, stb4, spi, nb, cnt);
        if (a1) noobj_row(j1, r1, stb4, spi, nb, cnt);

        #pragma unroll
        for (int off = 32; off > 0; off >>= 1){
            nb  += __shfl_down(nb, off);
            cnt += __shfl_down(cnt, off);
        }
        __shared__ float ws_s[4];
        __shared__ int   ws_c[4];
        const int wid = tid >> 6;
        if ((tid & 63) == 0){ ws_s[wid] = nb; ws_c[wid] = cnt; }
        __syncthreads();
        if (tid == 0){
            part_s[b*NBLK2 + x] = ws_s[0]+ws_s[1]+ws_s[2]+ws_s[3];
            part_c[b*NBLK2 + x] = ws_c[0]+ws_c[1]+ws_c[2]+ws_c[3];
        }
    } else {
        // ---- target path: one wave per target, fully parallel ----
        const int w    = tid >> 6;
        const int lane = tid & 63;
        const int t    = (x - NBLK2)*4 + w;      // 0..19
        float4 box = ((const float4*)tb)[b*NT + t];
        int pidx; float fx, fy, gtw, gth;
        target_decode(box.x, box.y, box.z, box.w, pidx, fx, fy, gtw, gth);
        const float* p = row_base(f0,f1,f2,b,pidx);
        const int lab = tlab[b*NT + t];
        float s;
        {
            float pc = sigm(p[5+lane]);
            float lg  = fmaxf(logf(pc),    -100.f);
            float lg1 = fmaxf(log1pf(-pc), -100.f);
            float tt = (lane == lab) ? 1.f : 0.f;
            s = -(tt*lg + (1.f-tt)*lg1);
        }
        if (lane < 16){
            int c = 64 + lane;
            float pc = sigm(p[5+c]);
            float lg  = fmaxf(logf(pc),    -100.f);
            float lg1 = fmaxf(log1pf(-pc), -100.f);
            float tt = (c == lab) ? 1.f : 0.f;
            s += -(tt*lg + (1.f-tt)*lg1);
        }
        #pragma unroll
        for (int off = 32; off > 0; off >>= 1) s += __shfl_down(s, off);
        if (lane == 0){
            const float w2 = 2.f - gtw*gth;
            float d0 = sigm(p[0]) - fx;
            float d1 = sigm(p[1]) - fy;
            float d2 = p[2] - gtw;
            float d3 = p[3] - gth;
            pbox[b*NT + t] = w2*(d0*d0 + d1*d1 + d2*d2 + d3*d3);
            float po = sigm(p[4]);
            float ts = tsc[b*NT + t];
            float lg  = fmaxf(logf(po),    -100.f);
            float lg1 = fmaxf(log1pf(-po), -100.f);
            pobj[b*NT + t] = -(ts*lg + (1.f-ts)*lg1);
            pcls[b*NT + t] = s;
        }
    }
}

// ---------------- Finalize ----------------
__global__ __launch_bounds__(256) void yolo_final(
        const float* __restrict__ part_s, const int* __restrict__ part_c,
        const float* __restrict__ pbox, const float* __restrict__ pobj,
        const float* __restrict__ pcls, float* __restrict__ out){
    const int tid  = threadIdx.x;
    const int w    = tid >> 6;
    const int lane = tid & 63;
    __shared__ float rb[NB], ro[NB], rc[NB], rn[NB];
    for (int b = w; b < NB; b += 4){
        float s = 0.f; int c = 0;
        if (lane < NBLK2){ s = part_s[b*NBLK2 + lane]; c = part_c[b*NBLK2 + lane]; }
        float A = 0.f, O = 0.f, C = 0.f;
        if (lane < NT){ A = pbox[b*NT + lane]; O = pobj[b*NT + lane]; C = pcls[b*NT + lane]; }
        #pragma unroll
        for (int off = 32; off > 0; off >>= 1){
            s += __shfl_down(s, off);
            c += __shfl_down(c, off);
            A += __shfl_down(A, off);
            O += __shfl_down(O, off);
            C += __shfl_down(C, off);
        }
        if (lane == 0){
            float lb = A/(float)(NT*4);
            if (isinf(lb)) lb = 0.f;
            rb[b] = lb;
            ro[b] = O/(float)NT;
            rc[b] = C/(float)(NT*80);
            rn[b] = s/(float)(c > 1 ? c : 1);
        }
    }
    __syncthreads();
    if (tid == 0){
        float sb=0.f, so=0.f, sc=0.f, sn=0.f;
        for (int b = 0; b < NB; ++b){ sb += rb[b]; so += ro[b]; sc += rc[b]; sn += rn[b]; }
        out[0] = sb/(float)NB;          // L_COORD * lbox.mean()
        out[1] = sc/(float)NB;          // L_CLS   * lcls.mean()
        out[2] = so/(float)NB;          // L_OBJ   * lobj.mean()
        out[3] = 0.5f*sn/(float)NB;     // L_NOOBJ * lnoobj.mean()
    }
}

extern "C" void kernel_launch(void* const* d_in, const int* in_sizes, int n_in,
                              void* d_out, int out_size, void* d_ws, size_t ws_size,
                              hipStream_t stream) {
    const float* f0  = (const float*)d_in[0];
    const float* f1  = (const float*)d_in[1];
    const float* f2  = (const float*)d_in[2];
    const float* tb  = (const float*)d_in[3];
    const int*   tlab= (const int*)  d_in[4];
    const float* tsc = (const float*)d_in[5];
    float* out = (float*)d_out;

    // ws layout — every slot written every call; no init needed
    char* ws = (char*)d_ws;
    float* part_s = (float*)ws;                       // 16*45 floats = 2880 B
    int*   part_c = (int*)  (ws + 2880);              // 16*45 ints  = 2880 B
    float* pbox   = (float*)(ws + 5760);              // 320 f
    float* pobj   = (float*)(ws + 7040);              // 320 f
    float* pcls   = (float*)(ws + 8320);              // 320 f

    dim3 grid(NBLK2 + NTBLK, NB);
    yolo_fused<<<grid, 256, 0, stream>>>(f0, f1, f2, tb, tlab, tsc,
                                         part_s, part_c, pbox, pobj, pcls);
    yolo_final<<<1, 256, 0, stream>>>(part_s, part_c, pbox, pobj, pcls, out);
}